// Round 6
// baseline (231.713 us; speedup 1.0000x reference)
//
#include <hip/hip_runtime.h>
#include <math.h>

// DCT2net, R6: two kernels, lane = (col, kj) coordinate, barrier-free main loop.
//
// K2 (dct2net_k2): per 16-lane group (13 kj used), one patch column.
//   Streams rows down a 31-output-row segment (16 segments -> 1024 blocks,
//   16 waves/CU at VGPR<=128):
//     hDCT (x via ds_bpermute from 16 loader lanes) -> 13-reg ring Rv
//     vDCT + shrink (even/odd symmetry) -> tn[13], pnz
//     w = 1/(1+sum nz) via 4-step __shfl_xor butterfly in the 16-group
//     fold (scaled by w) -> 13-reg ring Hr;  w box-sum -> 13-reg ring Wr
//     retire: Hg[img][a][col][16] = Hr[0];  Wg[img][a][col] = Wr[0] (jj==0)
//   NO __syncthreads in the loop; no cross-wave traffic at all.
// K3 (dct2net_k3): per out row, 52 out cols/wave (64 lanes = 52 out + 12 halo,
//   single U-build pass): U[c][dy] = sum_j c1[dy][j] H[a][c][j] (169 FMA),
//   out = sum_dy U[b+12-dy][dy] / sum_d Wsum[b+d]. Same-wave LDS only.
//
// ws layout: Hg = 2*488*512*16 f32 (31.98 MB), Wg = 2*488*512 f32 (2.0 MB).

#define P13    13
#define IMGW   512
#define OUTW   488
#define SEGH   31      // H rows per K2 segment; 16*31 = 496 >= 488
#define NSEG   16
#define HCOLS  512     // padded col dim of Hg
#define HPITCH 16      // padded j dim of Hg

struct C1mat { float v[P13 * P13]; };  // v[x*13+k] = sqrt(2/13)*Ci[k]*cos((2x+1)k*pi/26)

__device__ __forceinline__ void vdct_shrink(const float (&Rv)[P13], const C1mat& c1,
                                            float inv3s, float (&tn)[P13], float& pnz)
{
    float Se[6], So[6];
#pragma unroll
    for (int k = 0; k < 6; ++k) { Se[k] = Rv[k] + Rv[12 - k]; So[k] = Rv[k] - Rv[12 - k]; }
#pragma unroll
    for (int i = 0; i < P13; ++i) {
        float t;
        if ((i & 1) == 0) {
            t = c1.v[6 * P13 + i] * Rv[6];
#pragma unroll
            for (int k = 0; k < 6; ++k) t = fmaf(c1.v[k * P13 + i], Se[k], t);
        } else {
            t = c1.v[0 * P13 + i] * So[0];
#pragma unroll
            for (int k = 1; k < 6; ++k) t = fmaf(c1.v[k * P13 + i], So[k], t);
        }
        float u = t * inv3s;
        u = __builtin_amdgcn_fmed3f(u, -1.3f, 1.3f);   // clamp: u^64 <= 2e7, nz err ~5e-8
        float p2 = u * u, p4 = p2 * p2, p8 = p4 * p4;
        float p16 = p8 * p8, p32 = p16 * p16, p64 = p32 * p32;
        float nz = p64 * __builtin_amdgcn_rcpf(p64 + 1.0f);
        pnz += nz;
        tn[i] = t * nz;
    }
}

__device__ __forceinline__ void fold_vert(float (&tn)[P13], const C1mat& c1,
                                          float w1, float (&H)[P13])
{
#pragma unroll
    for (int i = 0; i < P13; ++i) tn[i] *= w1;
#pragma unroll
    for (int dx = 0; dx < 6; ++dx) {
        float E = c1.v[dx * P13 + 0] * tn[0];
#pragma unroll
        for (int i = 2; i < P13; i += 2) E = fmaf(c1.v[dx * P13 + i], tn[i], E);
        float O = c1.v[dx * P13 + 1] * tn[1];
#pragma unroll
        for (int i = 3; i < P13; i += 2) O = fmaf(c1.v[dx * P13 + i], tn[i], O);
        H[dx]      += E + O;
        H[12 - dx] += E - O;
    }
    float z6 = c1.v[6 * P13 + 0] * tn[0];
#pragma unroll
    for (int i = 2; i < P13; i += 2) z6 = fmaf(c1.v[6 * P13 + i], tn[i], z6);
    H[6] += z6;
}

__global__ __launch_bounds__(256) void dct2net_k2(
    const float* __restrict__ xg, const float* __restrict__ sigmag,
    float* __restrict__ Hg, float* __restrict__ Wg, C1mat c1)
{
    __shared__ float c1lds[169];
    const int tid = threadIdx.x;
    if (tid < 169) c1lds[tid] = c1.v[tid];
    __syncthreads();                       // once, for the c1 table only

    const int lane = tid & 63;
    const int wv   = tid >> 6;             // wave 0..3
    const int g    = lane >> 4;            // col group 0..3 within wave
    const int jj   = lane & 15;            // kj (0..12 used, 13..15 idle)
    const int img  = blockIdx.z;
    const int hs   = blockIdx.y * SEGH;    // first H row of this segment
    const int cbw  = blockIdx.x * 16 + wv * 4;   // wave's first col
    const int col  = cbw + g;              // this lane's patch column (0..511)

    const float inv3s = 1.0f / (3.0f * sigmag[0]);
    const float* xin  = xg + (size_t)img * IMGW * IMGW;

    // per-lane c1 column for the hDCT (j = jj), from the LDS table
    float c1col[P13];
    {
        const int jc = (jj < 13) ? jj : 12;
#pragma unroll
        for (int y = 0; y < P13; ++y) c1col[y] = c1lds[y * P13 + jc];
    }

    float Rv[P13], Hr[P13], Wr[P13];
#pragma unroll
    for (int k = 0; k < P13; ++k) { Rv[k] = 0.0f; Hr[k] = 0.0f; Wr[k] = 0.0f; }

    int xcol = cbw + lane; xcol = (xcol < IMGW - 1) ? xcol : (IMGW - 1);
    float xv = 0.0f;
    if (lane < 16) xv = xin[(size_t)hs * IMGW + xcol];   // row hs, cols cbw..cbw+15

    // steps k=0..54: load/hDCT row hs+k; k>=12: patch row hs+k-12; k>=24: H row hs+k-24
    for (int k = 0; k <= SEGH + 23; ++k) {
        // gather this wave's 16 staged x values via bpermute (sliding 13-window)
        float xw[P13];
#pragma unroll
        for (int y = 0; y < P13; ++y)
            xw[y] = __int_as_float(
                __builtin_amdgcn_ds_bpermute(4 * (g + y), __float_as_int(xv)));
        {   // prefetch next row (consumed next iteration -> latency hidden)
            int nr = hs + k + 1; nr = (nr < IMGW) ? nr : (IMGW - 1);
            if (lane < 16) xv = xin[(size_t)nr * IMGW + xcol];
        }
        // hDCT: two partial FMA chains
        float a0 = c1col[0] * xw[0], a1 = c1col[1] * xw[1];
#pragma unroll
        for (int y = 2; y < P13; y += 2) a0 = fmaf(c1col[y], xw[y], a0);
#pragma unroll
        for (int y = 3; y < P13; y += 2) a1 = fmaf(c1col[y], xw[y], a1);
#pragma unroll
        for (int q = 0; q < P13 - 1; ++q) Rv[q] = Rv[q + 1];
        Rv[P13 - 1] = a0 + a1;

        if (k >= 12) {
            float tn[P13]; float pnz = 0.0f;
            vdct_shrink(Rv, c1, inv3s, tn, pnz);
            if (jj >= 13) pnz = 0.0f;      // idle lanes contribute 0
            // 16-lane butterfly: every lane of the group gets sum of 13 pnz
            pnz += __shfl_xor(pnz, 1, 16);
            pnz += __shfl_xor(pnz, 2, 16);
            pnz += __shfl_xor(pnz, 4, 16);
            pnz += __shfl_xor(pnz, 8, 16);
            const float w = __builtin_amdgcn_rcpf(1.0f + pnz);
            fold_vert(tn, c1, w, Hr);
#pragma unroll
            for (int dx = 0; dx < P13; ++dx) Wr[dx] += w;
            if (k >= 24) {                 // H row a complete (folds from rows a..a+12)
                const int a = hs + k - 24;
                if (a < OUTW) {
                    Hg[(((size_t)img * OUTW + a) * HCOLS + col) * HPITCH + jj] = Hr[0];
                    if (jj == 0) Wg[((size_t)img * OUTW + a) * IMGW + col] = Wr[0];
                }
            }
#pragma unroll
            for (int q = 0; q < P13 - 1; ++q) { Hr[q] = Hr[q + 1]; Wr[q] = Wr[q + 1]; }
            Hr[P13 - 1] = 0.0f; Wr[P13 - 1] = 0.0f;
        }
    }
}

__global__ __launch_bounds__(256) void dct2net_k3(
    const float* __restrict__ Hg, const float* __restrict__ Wg,
    float* __restrict__ outg, C1mat c1)
{
    // 52 out cols per wave; 64 lanes = 52 out + 12 halo -> single U-build pass.
    // Arrays sized 80 so halo reads (index <= 75, garbage, masked) stay in-bounds.
    __shared__ float U[4][80][14];   // stride 14: 2-way bank alias only (free)
    __shared__ float vw[4][80];
    const int tid  = threadIdx.x;
    const int lane = tid & 63;
    const int wv   = tid >> 6;
    const int img  = blockIdx.z;
    const int a    = blockIdx.y * 4 + wv;      // out row (< 488)
    const int cb   = blockIdx.x * 52;          // out col base

    int c = cb + lane; c = (c <= 499) ? c : 499;   // clamp; clamped slots masked
    const float* hp = &Hg[(((size_t)img * OUTW + a) * HCOLS + c) * HPITCH];
    float hv[P13];
    *(float4*)&hv[0] = *(const float4*)hp;
    *(float4*)&hv[4] = *(const float4*)(hp + 4);
    *(float4*)&hv[8] = *(const float4*)(hp + 8);
    hv[12] = hp[12];
#pragma unroll
    for (int dy = 0; dy < P13; ++dy) {
        float s0 = c1.v[dy * P13 + 0] * hv[0];
        float s1 = c1.v[dy * P13 + 1] * hv[1];
#pragma unroll
        for (int j = 2; j < P13; j += 2) s0 = fmaf(c1.v[dy * P13 + j], hv[j], s0);
#pragma unroll
        for (int j = 3; j < P13; j += 2) s1 = fmaf(c1.v[dy * P13 + j], hv[j], s1);
        U[wv][lane][dy] = s0 + s1;
    }
    vw[wv][lane] = Wg[((size_t)img * OUTW + a) * IMGW + c];   // Wsum from K2

    // same-wave LDS write->read: program order, no barrier needed
    float num = 0.0f;
#pragma unroll
    for (int dy = 0; dy < P13; ++dy) num += U[wv][lane + 12 - dy][dy];
    float den = 0.0f;
#pragma unroll
    for (int d = 0; d < P13; ++d) den += vw[wv][lane + d];
    const int ow = cb + lane;
    if (lane < 52 && ow < OUTW)
        outg[((size_t)img * OUTW + a) * OUTW + ow] = num * __builtin_amdgcn_rcpf(den);
}

extern "C" void kernel_launch(void* const* d_in, const int* in_sizes, int n_in,
                              void* d_out, int out_size, void* d_ws, size_t ws_size,
                              hipStream_t stream)
{
    const float* x     = (const float*)d_in[0];
    const float* sigma = (const float*)d_in[1];
    float* out = (float*)d_out;

    C1mat c1;
    const double PI = 3.14159265358979323846;
    for (int xx = 0; xx < 13; ++xx)
        for (int k = 0; k < 13; ++k) {
            double Ci = (k == 0) ? (1.0 / sqrt(2.0)) : 1.0;
            c1.v[xx * 13 + k] =
                (float)(sqrt(2.0 / 13.0) * Ci * cos((2 * xx + 1) * k * PI / 26.0));
        }

    // ws: Hg (2*488*512*16 f32 = 31.98 MB) then Wg (2*488*512 f32 = 2.0 MB)
    float* Hg = (float*)d_ws;
    float* Wg = Hg + (size_t)2 * OUTW * HCOLS * HPITCH;

    dct2net_k2<<<dim3(32, NSEG, 2), 256, 0, stream>>>(x, sigma, Hg, Wg, c1);
    dct2net_k3<<<dim3(10, 122, 2), 256, 0, stream>>>(Hg, Wg, out, c1);
}